// Round 1
// 325.827 us; speedup vs baseline: 1.0632x; 1.0632x over previous
//
#include <hip/hip_runtime.h>
#include <hip/hip_bf16.h>

#define N_ 384
#define C_ 128
#define M_ (N_*N_)   // 147456 rows (i*384+j)

typedef __attribute__((ext_vector_type(8))) short bf16x8_t;
typedef __attribute__((ext_vector_type(4))) float f32x4_t;
typedef unsigned int u32;
typedef unsigned short u16;

__device__ __forceinline__ u16 f2bf(float f) {
  u32 u = __builtin_bit_cast(u32, f);
  u32 r = (u + 0x7FFFu + ((u >> 16) & 1u)) >> 16;
  return (u16)r;
}
__device__ __forceinline__ float bf2f(u16 h) {
  u32 u = ((u32)h) << 16;
  return __builtin_bit_cast(float, u);
}

// ---------------- prep kernels ----------------
__global__ __launch_bounds__(256) void k_prep1(const float* __restrict__ lg, const float* __restrict__ rg,
    const float* __restrict__ Wl, const float* __restrict__ Wr, const float* __restrict__ Wg,
    const float* __restrict__ Wo, u16* __restrict__ wcat, u16* __restrict__ wot) {
  int idx = blockIdx.x*256 + threadIdx.x;
  if (idx < 49152) {
    int n = idx >> 7, k = idx & 127;
    float v;
    if (n < 128)      v = lg[k] * Wl[k*128 + n];
    else if (n < 256) v = rg[k] * Wr[k*128 + (n-128)];
    else              v = Wg[k*128 + (n-256)];
    wcat[idx] = f2bf(v);
  } else {
    int i2 = idx - 49152;           // < 16384
    int c = i2 >> 7, h = i2 & 127;
    wot[i2] = f2bf(Wo[h*128 + c]);
  }
}

__global__ __launch_bounds__(512) void k_prep2(const float* __restrict__ lb, const float* __restrict__ rb,
    const float* __restrict__ Wl, const float* __restrict__ Wr, const float* __restrict__ Wg,
    const float* __restrict__ bl, const float* __restrict__ br, const float* __restrict__ bg,
    float* __restrict__ bcat, float* __restrict__ sg) {
  int t = threadIdx.x;
  if (blockIdx.x == 0) {
    if (t < 384) {
      float s = 0.f;
      if (t < 128)      { for (int k=0;k<128;k++) s += lb[k]*Wl[k*128+t];       s += bl[t];     }
      else if (t < 256) { int h=t-128; for (int k=0;k<128;k++) s += rb[k]*Wr[k*128+h]; s += br[h]; }
      else              { s = bg[t-256]; }
      bcat[t] = s;
    }
  } else {
    if (t < 128) {
      float s = 0.f;
      for (int k=0;k<128;k++) s += Wg[k*128+t];
      sg[t] = s;
    }
  }
}

#define LDK 136  // u16 stride of staged 128-k rows
#define LDA 72
#define LDW 72

// ---------------- K1: fused LN + ALL THREE projections per block ----------------
// 1152 blocks = 1152 row-chunks. LN computed ONCE per chunk; nb=0,1,2 looped
// inside the block reusing the staged normalized At tile (pair read exactly once).
__global__ __launch_bounds__(256) void k_projln(const float* __restrict__ pair,
    const u16* __restrict__ wcat, const float* __restrict__ bcat, const float* __restrict__ sg,
    u16* __restrict__ left_t, u16* __restrict__ right_t, u16* __restrict__ gate_t) {
  __shared__ u16 At[128*LDK];   // 34816 B
  __shared__ u16 Tt[64*LDK];    // 17408 B
  __shared__ float mu_s[128];
  __shared__ float irs_s[128];
  int bx = blockIdx.x;
  int r0 = bx * 128;
  int t = threadIdx.x, w = t>>6, lane = t&63;
  int q = lane>>4, nl = lane&15;

  // ---- LN phase: 2 threads per row (executed ONCE) ----
  {
    int rr = t >> 1, half = t & 1;
    const float4* gp = (const float4*)(pair + (size_t)(r0+rr)*128 + half*64);
    float4 v[16];
    #pragma unroll
    for (int i=0;i<16;i++) v[i] = gp[i];
    float s=0.f, qq=0.f;
    #pragma unroll
    for (int i=0;i<16;i++) {
      s  += v[i].x + v[i].y + v[i].z + v[i].w;
      qq += v[i].x*v[i].x + v[i].y*v[i].y + v[i].z*v[i].z + v[i].w*v[i].w;
    }
    s  += __shfl_xor(s, 1, 64);
    qq += __shfl_xor(qq, 1, 64);
    float mu = s * (1.f/128.f);
    float var = qq*(1.f/128.f) - mu*mu;
    float rstd = rsqrtf(var + 1e-5f);
    if (half == 0) { mu_s[rr] = mu; irs_s[rr] = 1.0f/rstd; }
    u32* lp = (u32*)(At + rr*LDK + half*64);
    #pragma unroll
    for (int i=0;i<8;i++) {
      u32 p0 = (u32)f2bf((v[2*i].x-mu)*rstd)   | ((u32)f2bf((v[2*i].y-mu)*rstd)<<16);
      u32 p1 = (u32)f2bf((v[2*i].z-mu)*rstd)   | ((u32)f2bf((v[2*i].w-mu)*rstd)<<16);
      u32 p2 = (u32)f2bf((v[2*i+1].x-mu)*rstd) | ((u32)f2bf((v[2*i+1].y-mu)*rstd)<<16);
      u32 p3 = (u32)f2bf((v[2*i+1].z-mu)*rstd) | ((u32)f2bf((v[2*i+1].w-mu)*rstd)<<16);
      ((uint4*)lp)[i] = make_uint4(p0,p1,p2,p3);
    }
  }
  __syncthreads();

  float muv[2][4], irv[2][4];
  #pragma unroll
  for (int tm=0;tm<2;tm++)
    #pragma unroll
    for (int p=0;p<4;p++) {
      int m = w*32 + tm*16 + q*4 + p;
      muv[tm][p] = mu_s[m];
      irv[tm][p] = irs_s[m];
    }

  for (int nb = 0; nb < 3; ++nb) {
    f32x4_t acc[2][8] = {};
    const u16* bbase = wcat + (size_t)(nb*128)*128;
    #pragma unroll
    for (int ks=0; ks<4; ks++) {
      int kel = ks*32 + q*8;
      bf16x8_t a0 = *(const bf16x8_t*)(At + (w*32      + nl)*LDK + kel);
      bf16x8_t a1 = *(const bf16x8_t*)(At + (w*32 + 16 + nl)*LDK + kel);
      #pragma unroll
      for (int tn=0;tn<8;tn++) {
        bf16x8_t b = *(const bf16x8_t*)(bbase + (size_t)(tn*16+nl)*128 + kel);
        acc[0][tn] = __builtin_amdgcn_mfma_f32_16x16x32_bf16(a0, b, acc[0][tn], 0,0,0);
        acc[1][tn] = __builtin_amdgcn_mfma_f32_16x16x32_bf16(a1, b, acc[1][tn], 0,0,0);
      }
    }
    u16* dst = (nb==0) ? left_t : (nb==1) ? right_t : gate_t;
    for (int nhalf=0; nhalf<2; nhalf++) {
      #pragma unroll
      for (int tm=0;tm<2;tm++)
        #pragma unroll
        for (int tn4=0;tn4<4;tn4++) {
          int tn = nhalf*4 + tn4;
          int n = tn*16 + nl;
          float bias = bcat[nb*128 + n];
          float sgn = (nb==2) ? sg[n] : 0.f;
          f32x4_t a4 = acc[tm][tn];
          float o[4];
          #pragma unroll
          for (int p=0;p<4;p++) {
            float v = a4[p];
            if (nb == 2) {
              v = v*irv[tm][p] + muv[tm][p]*sgn + bias;
              v = 1.0f / (1.0f + __expf(-v));
            } else {
              v += bias;
            }
            o[p] = v;
          }
          int m = w*32 + tm*16 + q*4;
          u32* wp = (u32*)(Tt + (tn4*16+nl)*LDK + m);
          wp[0] = (u32)f2bf(o[0]) | ((u32)f2bf(o[1])<<16);
          wp[1] = (u32)f2bf(o[2]) | ((u32)f2bf(o[3])<<16);
        }
      __syncthreads();
      {
        // full row copy: 4 threads/row x 32 u16 (4x uint4) = 128 u16 per row
        int nr = t>>2, q4 = t&3;
        const uint4* lp = (const uint4*)(Tt + nr*LDK + q4*32);
        u16* gp = dst + (size_t)(nhalf*64+nr)*M_ + r0 + q4*32;
        ((uint4*)gp)[0] = lp[0];
        ((uint4*)gp)[1] = lp[1];
        ((uint4*)gp)[2] = lp[2];
        ((uint4*)gp)[3] = lp[3];
      }
      __syncthreads();
    }
  }
}

// ---------------- K2: triangle einsum per h + gate multiply ----------------
// B staged from right_t[h][k][j] with in-LDS transpose (no separate transpose kernel).
__global__ __launch_bounds__(256) void k_einsum(const u16* __restrict__ left_t, const u16* __restrict__ right_t,
    const u16* __restrict__ gate_t, u16* __restrict__ og_t) {
  __shared__ u16 smem[2*128*LDA];  // 36864 B
  u16* At = smem; u16* Bt = smem + 128*LDA;
  int bx = blockIdx.x;
  int h = bx / 9; int rem = bx % 9;
  int i0 = (rem/3)*128, j0 = (rem%3)*128;
  const u16* Ag = left_t + (size_t)h*M_;
  const u16* Bg = right_t + (size_t)h*M_;
  int t = threadIdx.x, w = t>>6, lane = t&63;
  int q = lane>>4, nl = lane&15;
  f32x4_t acc[4][4] = {};
  int m0 = (w&1)*64, n0 = (w>>1)*64;
  for (int kb = 0; kb < N_; kb += 64) {
    { // stage A: left_t rows (i), k contiguous — direct vector copy
      int rr = t>>1, half = t&1;
      const u16* gp = Ag + (size_t)(i0+rr)*N_ + kb + half*32;
      u16* lp = At + rr*LDA + half*32;
      #pragma unroll
      for (int i=0;i<4;i++) ((uint4*)lp)[i] = ((const uint4*)gp)[i];
    }
    { // stage B with transpose: right_t[(kb+kk)*384 + j0+j] -> Bt[j][kk]
      int kk = t>>2, seg = t&3;
      const u16* gq = Bg + (size_t)(kb+kk)*N_ + j0 + seg*32;
      uint4 bb[4];
      #pragma unroll
      for (int i=0;i<4;i++) bb[i] = ((const uint4*)gq)[i];
      #pragma unroll
      for (int i=0;i<4;i++) {
        int jb = seg*32 + i*8;
        u32 x0=bb[i].x, x1=bb[i].y, x2=bb[i].z, x3=bb[i].w;
        Bt[(jb+0)*LDA+kk] = (u16)(x0&0xffffu); Bt[(jb+1)*LDA+kk] = (u16)(x0>>16);
        Bt[(jb+2)*LDA+kk] = (u16)(x1&0xffffu); Bt[(jb+3)*LDA+kk] = (u16)(x1>>16);
        Bt[(jb+4)*LDA+kk] = (u16)(x2&0xffffu); Bt[(jb+5)*LDA+kk] = (u16)(x2>>16);
        Bt[(jb+6)*LDA+kk] = (u16)(x3&0xffffu); Bt[(jb+7)*LDA+kk] = (u16)(x3>>16);
      }
    }
    __syncthreads();
    for (int ks=0; ks<2; ks++) {
      int kel = ks*32 + q*8;
      bf16x8_t a[4], b[4];
      #pragma unroll
      for (int tm=0;tm<4;tm++) a[tm] = *(const bf16x8_t*)(At + (m0+tm*16+nl)*LDA + kel);
      #pragma unroll
      for (int tn=0;tn<4;tn++) b[tn] = *(const bf16x8_t*)(Bt + (n0+tn*16+nl)*LDA + kel);
      #pragma unroll
      for (int tm=0;tm<4;tm++)
        #pragma unroll
        for (int tn=0;tn<4;tn++)
          acc[tm][tn] = __builtin_amdgcn_mfma_f32_16x16x32_bf16(a[tm], b[tn], acc[tm][tn], 0,0,0);
    }
    __syncthreads();
  }
  // epilogue: acc -> LDS bf16 [m][n], then gate-multiplied coalesced store (og_t[h][r])
#define LDT 136
  u16* Ot = smem;  // 128*LDT u16 = 34816 B <= 36864
  #pragma unroll
  for (int tm=0;tm<4;tm++)
    #pragma unroll
    for (int tn=0;tn<4;tn++)
      #pragma unroll
      for (int p=0;p<4;p++) {
        int m = m0 + tm*16 + q*4 + p;
        int n = n0 + tn*16 + nl;
        Ot[m*LDT + n] = f2bf(acc[tm][tn][p]);
      }
  __syncthreads();
  {
    int m = t>>1, half = t&1;
    size_t rbase = (size_t)h*M_ + (size_t)(i0+m)*N_ + j0 + half*64;
    const uint4* gg = (const uint4*)(gate_t + rbase);
    const uint4* lo = (const uint4*)(Ot + m*LDT + half*64);
    uint4* od = (uint4*)(og_t + rbase);
    #pragma unroll
    for (int i=0;i<8;i++) {
      uint4 gv = gg[i]; uint4 ov = lo[i];
      u32 ga[4] = {gv.x,gv.y,gv.z,gv.w};
      u32 oa[4] = {ov.x,ov.y,ov.z,ov.w};
      u32 ra[4];
      #pragma unroll
      for (int e=0;e<4;e++) {
        float g0 = bf2f((u16)(ga[e]&0xffffu)), g1 = bf2f((u16)(ga[e]>>16));
        float o0 = bf2f((u16)(oa[e]&0xffffu)), o1 = bf2f((u16)(oa[e]>>16));
        ra[e] = (u32)f2bf(o0*g0) | ((u32)f2bf(o1*g1)<<16);
      }
      od[i] = make_uint4(ra[0],ra[1],ra[2],ra[3]);
    }
  }
}

// ---------------- K3: og @ Wo + bo + pair, rowwise LN, fp32 out ----------------
// A staged from og_t[h][r] with in-LDS transpose (no separate transpose kernel).
__global__ __launch_bounds__(256) void k_final(const u16* __restrict__ og_t, const u16* __restrict__ wot,
    const float* __restrict__ pair, const float* __restrict__ bo,
    const float* __restrict__ ng, const float* __restrict__ nb_,
    float* __restrict__ out) {
  __shared__ u16 smem[2*128*LDW];  // 36864 B
  u16* At = smem; u16* Wt = smem + 128*LDW;
  int bx = blockIdx.x;
  int r0 = bx * 128;
  int t = threadIdx.x, w = t>>6, lane = t&63;
  int q = lane>>4, nl = lane&15;
  f32x4_t acc[2][8] = {};
  for (int c0 = 0; c0 < 128; c0 += 64) {
    { // stage A with transpose: og_t[(c0+hh)*M + r0+r] -> At[r][hh]
      int hh = t>>2, seg = t&3;
      const u16* gp = og_t + (size_t)(c0+hh)*M_ + r0 + seg*32;
      uint4 bb[4];
      #pragma unroll
      for (int i=0;i<4;i++) bb[i] = ((const uint4*)gp)[i];
      #pragma unroll
      for (int i=0;i<4;i++) {
        int rb = seg*32 + i*8;
        u32 x0=bb[i].x, x1=bb[i].y, x2=bb[i].z, x3=bb[i].w;
        At[(rb+0)*LDW+hh] = (u16)(x0&0xffffu); At[(rb+1)*LDW+hh] = (u16)(x0>>16);
        At[(rb+2)*LDW+hh] = (u16)(x1&0xffffu); At[(rb+3)*LDW+hh] = (u16)(x1>>16);
        At[(rb+4)*LDW+hh] = (u16)(x2&0xffffu); At[(rb+5)*LDW+hh] = (u16)(x2>>16);
        At[(rb+6)*LDW+hh] = (u16)(x3&0xffffu); At[(rb+7)*LDW+hh] = (u16)(x3>>16);
      }
    }
    { // stage Wo chunk: Wt[c][h']
      int c = t>>1, half = t&1;
      const u16* gp = wot + (size_t)c*128 + c0 + half*32;
      u16* lp = Wt + c*LDW + half*32;
      #pragma unroll
      for (int i=0;i<4;i++) ((uint4*)lp)[i] = ((const uint4*)gp)[i];
    }
    __syncthreads();
    int mbase = w*32;
    for (int ks=0; ks<2; ks++) {
      int kel = ks*32 + q*8;
      bf16x8_t a[2], b[8];
      #pragma unroll
      for (int tm=0;tm<2;tm++) a[tm] = *(const bf16x8_t*)(At + (mbase+tm*16+nl)*LDW + kel);
      #pragma unroll
      for (int tn=0;tn<8;tn++) b[tn] = *(const bf16x8_t*)(Wt + (tn*16+nl)*LDW + kel);
      #pragma unroll
      for (int tm=0;tm<2;tm++)
        #pragma unroll
        for (int tn=0;tn<8;tn++)
          acc[tm][tn] = __builtin_amdgcn_mfma_f32_16x16x32_bf16(a[tm], b[tn], acc[tm][tn], 0,0,0);
    }
    __syncthreads();
  }
  // epilogue: residual + bias, transpose-free rowwise LN via 16-lane shfl reduction
  float rsum[2][4], rsq[2][4];
  for (int tm=0;tm<2;tm++) for (int p=0;p<4;p++) { rsum[tm][p]=0.f; rsq[tm][p]=0.f; }
  #pragma unroll
  for (int tm=0;tm<2;tm++)
    #pragma unroll
    for (int tn=0;tn<8;tn++) {
      int n = tn*16 + nl;
      float bb = bo[n];
      #pragma unroll
      for (int p=0;p<4;p++) {
        int m = w*32 + tm*16 + q*4 + p;
        float v = acc[tm][tn][p] + bb + pair[(size_t)(r0+m)*128 + n];
        acc[tm][tn][p] = v;
        rsum[tm][p] += v;
        rsq[tm][p]  += v*v;
      }
    }
  for (int msk=1; msk<16; msk<<=1) {
    #pragma unroll
    for (int tm=0;tm<2;tm++)
      #pragma unroll
      for (int p=0;p<4;p++) {
        rsum[tm][p] += __shfl_xor(rsum[tm][p], msk, 64);
        rsq[tm][p]  += __shfl_xor(rsq[tm][p],  msk, 64);
      }
  }
  #pragma unroll
  for (int tm=0;tm<2;tm++)
    #pragma unroll
    for (int p=0;p<4;p++) {
      float mu = rsum[tm][p] * (1.f/128.f);
      float var = rsq[tm][p]*(1.f/128.f) - mu*mu;
      rsum[tm][p] = mu;
      rsq[tm][p] = rsqrtf(var + 1e-5f);
    }
  #pragma unroll
  for (int tm=0;tm<2;tm++)
    #pragma unroll
    for (int tn=0;tn<8;tn++) {
      int n = tn*16 + nl;
      float g = ng[n], b2 = nb_[n];
      #pragma unroll
      for (int p=0;p<4;p++) {
        int m = w*32 + tm*16 + q*4 + p;
        out[(size_t)(r0+m)*128 + n] = (acc[tm][tn][p] - rsum[tm][p]) * rsq[tm][p] * g + b2;
      }
    }
}

extern "C" void kernel_launch(void* const* d_in, const int* in_sizes, int n_in,
                              void* d_out, int out_size, void* d_ws, size_t ws_size,
                              hipStream_t stream) {
  (void)in_sizes; (void)n_in; (void)out_size; (void)ws_size;
  const float* pair   = (const float*)d_in[0];
  const float* ln_l_g = (const float*)d_in[1];
  const float* ln_l_b = (const float*)d_in[2];
  const float* ln_r_g = (const float*)d_in[3];
  const float* ln_r_b = (const float*)d_in[4];
  const float* Wl = (const float*)d_in[5];
  const float* bl = (const float*)d_in[6];
  const float* Wr = (const float*)d_in[7];
  const float* br = (const float*)d_in[8];
  const float* Wg = (const float*)d_in[9];
  const float* bg = (const float*)d_in[10];
  const float* Wo = (const float*)d_in[11];
  const float* bo = (const float*)d_in[12];
  const float* n_g = (const float*)d_in[13];
  const float* n_b = (const float*)d_in[14];

  char* ws = (char*)d_ws;
  const size_t SZ = (size_t)M_*128*sizeof(u16);         // 37,748,736 B
  u16*  og_t    = (u16*)(ws);                           // written by k_einsum
  u16*  gate_t  = (u16*)(ws + SZ);
  u16*  wcat    = (u16*)(ws + 2*SZ);
  float* bcat   = (float*)(ws + 2*SZ + 98304);
  float* sgp    = (float*)(ws + 2*SZ + 98304 + 1536);
  u16*  wot     = (u16*)(ws + 2*SZ + 98304 + 1536 + 512);

  // left_t / right_t live in d_out until k_final overwrites it with the result
  u16* left_t   = (u16*)d_out;
  u16* right_t  = (u16*)d_out + (size_t)M_*128;

  k_prep1<<<256, 256, 0, stream>>>(ln_l_g, ln_r_g, Wl, Wr, Wg, Wo, wcat, wot);
  k_prep2<<<2, 512, 0, stream>>>(ln_l_b, ln_r_b, Wl, Wr, Wg, bl, br, bg, bcat, sgp);
  k_projln<<<1152, 256, 0, stream>>>(pair, wcat, bcat, sgp, left_t, right_t, gate_t);
  k_einsum<<<1152, 256, 0, stream>>>(left_t, right_t, gate_t, og_t);
  k_final<<<1152, 256, 0, stream>>>(og_t, wot, pair, bo, n_g, n_b, (float*)d_out);
}

// Round 2
// 304.228 us; speedup vs baseline: 1.1387x; 1.0710x over previous
//
#include <hip/hip_runtime.h>
#include <hip/hip_bf16.h>

#define N_ 384
#define C_ 128
#define M_ (N_*N_)   // 147456 rows (i*384+j)

typedef __attribute__((ext_vector_type(8))) short bf16x8_t;
typedef __attribute__((ext_vector_type(4))) float f32x4_t;
typedef unsigned int u32;
typedef unsigned short u16;
typedef unsigned long long u64;

__device__ __forceinline__ u16 f2bf(float f) {
  u32 u = __builtin_bit_cast(u32, f);
  u32 r = (u + 0x7FFFu + ((u >> 16) & 1u)) >> 16;
  return (u16)r;
}
__device__ __forceinline__ float bf2f(u16 h) {
  u32 u = ((u32)h) << 16;
  return __builtin_bit_cast(float, u);
}

// ---------------- prep kernels ----------------
__global__ __launch_bounds__(256) void k_prep1(const float* __restrict__ lg, const float* __restrict__ rg,
    const float* __restrict__ Wl, const float* __restrict__ Wr, const float* __restrict__ Wg,
    const float* __restrict__ Wo, u16* __restrict__ wcat, u16* __restrict__ wot) {
  int idx = blockIdx.x*256 + threadIdx.x;
  if (idx < 49152) {
    int n = idx >> 7, k = idx & 127;
    float v;
    if (n < 128)      v = lg[k] * Wl[k*128 + n];
    else if (n < 256) v = rg[k] * Wr[k*128 + (n-128)];
    else              v = Wg[k*128 + (n-256)];
    wcat[idx] = f2bf(v);
  } else {
    int i2 = idx - 49152;           // < 16384
    int c = i2 >> 7, h = i2 & 127;
    wot[i2] = f2bf(Wo[h*128 + c]);
  }
}

__global__ __launch_bounds__(512) void k_prep2(const float* __restrict__ lb, const float* __restrict__ rb,
    const float* __restrict__ Wl, const float* __restrict__ Wr, const float* __restrict__ Wg,
    const float* __restrict__ bl, const float* __restrict__ br, const float* __restrict__ bg,
    float* __restrict__ bcat, float* __restrict__ sg) {
  int t = threadIdx.x;
  if (blockIdx.x == 0) {
    if (t < 384) {
      float s = 0.f;
      if (t < 128)      { for (int k=0;k<128;k++) s += lb[k]*Wl[k*128+t];       s += bl[t];     }
      else if (t < 256) { int h=t-128; for (int k=0;k<128;k++) s += rb[k]*Wr[k*128+h]; s += br[h]; }
      else              { s = bg[t-256]; }
      bcat[t] = s;
    }
  } else {
    if (t < 128) {
      float s = 0.f;
      for (int k=0;k<128;k++) s += Wg[k*128+t];
      sg[t] = s;
    }
  }
}

#define LDK 136  // u16 stride of staged 128-k rows
#define LDA 72
#define LDW 72

// ---------------- K1: fused LN + three projections, n-split waves, direct stores ----------------
// 1152 blocks. LN once -> At (bf16). Per nb: each wave owns 32 n-cols (distinct
// wcat fragments, 4x less L2 traffic), all 128 m from LDS. Output stored straight
// from acc as packed 8B stores (m-contiguous) -> zero epilogue barriers, no Tt.
__global__ __launch_bounds__(256) void k_projln(const float* __restrict__ pair,
    const u16* __restrict__ wcat, const float* __restrict__ bcat, const float* __restrict__ sg,
    u16* __restrict__ left_t, u16* __restrict__ right_t, u16* __restrict__ gate_t) {
  __shared__ u16 At[128*LDK];   // 34816 B
  __shared__ float mu_s[128];
  __shared__ float irs_s[128];
  int bx = blockIdx.x;
  int r0 = bx * 128;
  int t = threadIdx.x, w = t>>6, lane = t&63;
  int q = lane>>4, nl = lane&15;

  // ---- LN phase: 2 threads per row (executed ONCE) ----
  {
    int rr = t >> 1, half = t & 1;
    const float4* gp = (const float4*)(pair + (size_t)(r0+rr)*128 + half*64);
    float4 v[16];
    #pragma unroll
    for (int i=0;i<16;i++) v[i] = gp[i];
    float s=0.f, qq=0.f;
    #pragma unroll
    for (int i=0;i<16;i++) {
      s  += v[i].x + v[i].y + v[i].z + v[i].w;
      qq += v[i].x*v[i].x + v[i].y*v[i].y + v[i].z*v[i].z + v[i].w*v[i].w;
    }
    s  += __shfl_xor(s, 1, 64);
    qq += __shfl_xor(qq, 1, 64);
    float mu = s * (1.f/128.f);
    float var = qq*(1.f/128.f) - mu*mu;
    float rstd = rsqrtf(var + 1e-5f);
    if (half == 0) { mu_s[rr] = mu; irs_s[rr] = 1.0f/rstd; }
    u32* lp = (u32*)(At + rr*LDK + half*64);
    #pragma unroll
    for (int i=0;i<8;i++) {
      u32 p0 = (u32)f2bf((v[2*i].x-mu)*rstd)   | ((u32)f2bf((v[2*i].y-mu)*rstd)<<16);
      u32 p1 = (u32)f2bf((v[2*i].z-mu)*rstd)   | ((u32)f2bf((v[2*i].w-mu)*rstd)<<16);
      u32 p2 = (u32)f2bf((v[2*i+1].x-mu)*rstd) | ((u32)f2bf((v[2*i+1].y-mu)*rstd)<<16);
      u32 p3 = (u32)f2bf((v[2*i+1].z-mu)*rstd) | ((u32)f2bf((v[2*i+1].w-mu)*rstd)<<16);
      ((uint4*)lp)[i] = make_uint4(p0,p1,p2,p3);
    }
  }
  __syncthreads();

  #pragma unroll 1
  for (int nb = 0; nb < 3; ++nb) {
    const u16* bbase = wcat + (size_t)(nb*128)*128;
    f32x4_t acc[8][2] = {};   // [tm][tn] ; m = tm*16+q*4+p, n = w*32+tn*16+nl
    #pragma unroll
    for (int ks=0; ks<4; ks++) {
      int kel = ks*32 + q*8;
      bf16x8_t b0 = *(const bf16x8_t*)(bbase + (size_t)(w*32      + nl)*128 + kel);
      bf16x8_t b1 = *(const bf16x8_t*)(bbase + (size_t)(w*32 + 16 + nl)*128 + kel);
      #pragma unroll
      for (int tm=0;tm<8;tm++) {
        bf16x8_t a = *(const bf16x8_t*)(At + (tm*16+nl)*LDK + kel);
        acc[tm][0] = __builtin_amdgcn_mfma_f32_16x16x32_bf16(a, b0, acc[tm][0], 0,0,0);
        acc[tm][1] = __builtin_amdgcn_mfma_f32_16x16x32_bf16(a, b1, acc[tm][1], 0,0,0);
      }
    }
    u16* dst = (nb==0) ? left_t : (nb==1) ? right_t : gate_t;
    #pragma unroll
    for (int tn=0;tn<2;tn++) {
      int n = w*32 + tn*16 + nl;
      float bias = bcat[nb*128 + n];
      u16* rowp = dst + (size_t)n*M_ + r0;
      if (nb == 2) {
        float sgn = sg[n];
        #pragma unroll
        for (int tm=0;tm<8;tm++) {
          f32x4_t mu4 = *(const f32x4_t*)(mu_s  + tm*16 + q*4);
          f32x4_t ir4 = *(const f32x4_t*)(irs_s + tm*16 + q*4);
          u32 pk0, pk1;
          {
            float v0 = acc[tm][tn][0]*ir4[0] + mu4[0]*sgn + bias;
            float v1 = acc[tm][tn][1]*ir4[1] + mu4[1]*sgn + bias;
            float v2 = acc[tm][tn][2]*ir4[2] + mu4[2]*sgn + bias;
            float v3 = acc[tm][tn][3]*ir4[3] + mu4[3]*sgn + bias;
            v0 = 1.0f/(1.0f+__expf(-v0));
            v1 = 1.0f/(1.0f+__expf(-v1));
            v2 = 1.0f/(1.0f+__expf(-v2));
            v3 = 1.0f/(1.0f+__expf(-v3));
            pk0 = (u32)f2bf(v0) | ((u32)f2bf(v1)<<16);
            pk1 = (u32)f2bf(v2) | ((u32)f2bf(v3)<<16);
          }
          *(u64*)(rowp + tm*16 + q*4) = (u64)pk0 | ((u64)pk1<<32);
        }
      } else {
        #pragma unroll
        for (int tm=0;tm<8;tm++) {
          u32 pk0 = (u32)f2bf(acc[tm][tn][0]+bias) | ((u32)f2bf(acc[tm][tn][1]+bias)<<16);
          u32 pk1 = (u32)f2bf(acc[tm][tn][2]+bias) | ((u32)f2bf(acc[tm][tn][3]+bias)<<16);
          *(u64*)(rowp + tm*16 + q*4) = (u64)pk0 | ((u64)pk1<<32);
        }
      }
    }
  }
}

// ---------------- K2: triangle einsum per h + gate multiply ----------------
// B staged from right_t[h][k][j] with register pair-transpose (b32 LDS writes)
// and XOR swizzle  byte ^= (j>>4)<<4  applied on Bt writes AND fragment reads.
__global__ __launch_bounds__(256) void k_einsum(const u16* __restrict__ left_t, const u16* __restrict__ right_t,
    const u16* __restrict__ gate_t, u16* __restrict__ og_t) {
  __shared__ u16 smem[2*128*LDA];  // 36864 B
  u16* At = smem; u16* Bt = smem + 128*LDA;
  int bx = blockIdx.x;
  int h = bx / 9; int rem = bx % 9;
  int i0 = (rem/3)*128, j0 = (rem%3)*128;
  const u16* Ag = left_t + (size_t)h*M_;
  const u16* Bg = right_t + (size_t)h*M_;
  int t = threadIdx.x, w = t>>6, lane = t&63;
  int q = lane>>4, nl = lane&15;
  f32x4_t acc[4][4] = {};
  int m0 = (w&1)*64, n0 = (w>>1)*64;
  for (int kb = 0; kb < N_; kb += 64) {
    { // stage A: left_t rows (i), k contiguous — direct vector copy
      int rr = t>>1, half = t&1;
      const u16* gp = Ag + (size_t)(i0+rr)*N_ + kb + half*32;
      u16* lp = At + rr*LDA + half*32;
      #pragma unroll
      for (int i=0;i<4;i++) ((uint4*)lp)[i] = ((const uint4*)gp)[i];
    }
    { // stage B: register pair-transpose right_t[(kb+k)][j0+j] -> Bt[j][k] (swizzled)
      int kk2 = t>>3;          // 0..31 : k-pair
      int seg = t&7;           // j-chunk of 16
      const u16* g0 = Bg + (size_t)(kb + 2*kk2)*N_ + j0 + seg*16;
      const u16* g1 = g0 + N_;
      uint4 r0a = ((const uint4*)g0)[0], r0b = ((const uint4*)g0)[1];
      uint4 r1a = ((const uint4*)g1)[0], r1b = ((const uint4*)g1)[1];
      u32 w0[8] = {r0a.x,r0a.y,r0a.z,r0a.w,r0b.x,r0b.y,r0b.z,r0b.w};
      u32 w1[8] = {r1a.x,r1a.y,r1a.z,r1a.w,r1b.x,r1b.y,r1b.z,r1b.w};
      u32 sw = (u32)seg << 4;                 // j>>4 == seg for all j in chunk
      char* bbytes = (char*)Bt;
      #pragma unroll
      for (int e=0;e<8;e++) {
        u32 lo = w0[e], hi = w1[e];
        u32 evenw = (lo & 0xffffu) | (hi << 16);
        u32 oddw  = (lo >> 16)     | (hi & 0xffff0000u);
        int je = seg*16 + 2*e;
        u32 byteE = ((u32)(je*LDA + 2*kk2) * 2u) ^ sw;
        u32 byteO = ((u32)((je+1)*LDA + 2*kk2) * 2u) ^ sw;
        *(u32*)(bbytes + byteE) = evenw;
        *(u32*)(bbytes + byteO) = oddw;
      }
    }
    __syncthreads();
    for (int ks=0; ks<2; ks++) {
      int kel = ks*32 + q*8;
      bf16x8_t a[4], b[4];
      #pragma unroll
      for (int tm=0;tm<4;tm++) a[tm] = *(const bf16x8_t*)(At + (m0+tm*16+nl)*LDA + kel);
      #pragma unroll
      for (int tn=0;tn<4;tn++) {
        u32 swr = (u32)(((n0>>4) + tn) & 7) << 4;
        b[tn] = *(const bf16x8_t*)((const char*)Bt + ((u32)(((n0+tn*16+nl)*LDA + kel)*2) ^ swr));
      }
      #pragma unroll
      for (int tm=0;tm<4;tm++)
        #pragma unroll
        for (int tn=0;tn<4;tn++)
          acc[tm][tn] = __builtin_amdgcn_mfma_f32_16x16x32_bf16(a[tm], b[tn], acc[tm][tn], 0,0,0);
    }
    __syncthreads();
  }
  // epilogue: acc -> LDS bf16 [m][n], then gate-multiplied coalesced store (og_t[h][r])
#define LDT 136
  u16* Ot = smem;  // 128*LDT u16 = 34816 B <= 36864
  #pragma unroll
  for (int tm=0;tm<4;tm++)
    #pragma unroll
    for (int tn=0;tn<4;tn++)
      #pragma unroll
      for (int p=0;p<4;p++) {
        int m = m0 + tm*16 + q*4 + p;
        int n = n0 + tn*16 + nl;
        Ot[m*LDT + n] = f2bf(acc[tm][tn][p]);
      }
  __syncthreads();
  {
    int m = t>>1, half = t&1;
    size_t rbase = (size_t)h*M_ + (size_t)(i0+m)*N_ + j0 + half*64;
    const uint4* gg = (const uint4*)(gate_t + rbase);
    const uint4* lo = (const uint4*)(Ot + m*LDT + half*64);
    uint4* od = (uint4*)(og_t + rbase);
    #pragma unroll
    for (int i=0;i<8;i++) {
      uint4 gv = gg[i]; uint4 ov = lo[i];
      u32 ga[4] = {gv.x,gv.y,gv.z,gv.w};
      u32 oa[4] = {ov.x,ov.y,ov.z,ov.w};
      u32 ra[4];
      #pragma unroll
      for (int e=0;e<4;e++) {
        float g0 = bf2f((u16)(ga[e]&0xffffu)), g1 = bf2f((u16)(ga[e]>>16));
        float o0 = bf2f((u16)(oa[e]&0xffffu)), o1 = bf2f((u16)(oa[e]>>16));
        ra[e] = (u32)f2bf(o0*g0) | ((u32)f2bf(o1*g1)<<16);
      }
      od[i] = make_uint4(ra[0],ra[1],ra[2],ra[3]);
    }
  }
}

// ---------------- K3: og @ Wo + bo + pair, rowwise LN, fp32 out ----------------
// A staged from og_t[h][r] with in-LDS transpose (no separate transpose kernel).
__global__ __launch_bounds__(256) void k_final(const u16* __restrict__ og_t, const u16* __restrict__ wot,
    const float* __restrict__ pair, const float* __restrict__ bo,
    const float* __restrict__ ng, const float* __restrict__ nb_,
    float* __restrict__ out) {
  __shared__ u16 smem[2*128*LDW];  // 36864 B
  u16* At = smem; u16* Wt = smem + 128*LDW;
  int bx = blockIdx.x;
  int r0 = bx * 128;
  int t = threadIdx.x, w = t>>6, lane = t&63;
  int q = lane>>4, nl = lane&15;
  f32x4_t acc[2][8] = {};
  for (int c0 = 0; c0 < 128; c0 += 64) {
    { // stage A with transpose: og_t[(c0+hh)*M + r0+r] -> At[r][hh]
      int hh = t>>2, seg = t&3;
      const u16* gp = og_t + (size_t)(c0+hh)*M_ + r0 + seg*32;
      uint4 bb[4];
      #pragma unroll
      for (int i=0;i<4;i++) bb[i] = ((const uint4*)gp)[i];
      #pragma unroll
      for (int i=0;i<4;i++) {
        int rb = seg*32 + i*8;
        u32 x0=bb[i].x, x1=bb[i].y, x2=bb[i].z, x3=bb[i].w;
        At[(rb+0)*LDW+hh] = (u16)(x0&0xffffu); At[(rb+1)*LDW+hh] = (u16)(x0>>16);
        At[(rb+2)*LDW+hh] = (u16)(x1&0xffffu); At[(rb+3)*LDW+hh] = (u16)(x1>>16);
        At[(rb+4)*LDW+hh] = (u16)(x2&0xffffu); At[(rb+5)*LDW+hh] = (u16)(x2>>16);
        At[(rb+6)*LDW+hh] = (u16)(x3&0xffffu); At[(rb+7)*LDW+hh] = (u16)(x3>>16);
      }
    }
    { // stage Wo chunk: Wt[c][h']
      int c = t>>1, half = t&1;
      const u16* gp = wot + (size_t)c*128 + c0 + half*32;
      u16* lp = Wt + c*LDW + half*32;
      #pragma unroll
      for (int i=0;i<4;i++) ((uint4*)lp)[i] = ((const uint4*)gp)[i];
    }
    __syncthreads();
    int mbase = w*32;
    for (int ks=0; ks<2; ks++) {
      int kel = ks*32 + q*8;
      bf16x8_t a[2], b[8];
      #pragma unroll
      for (int tm=0;tm<2;tm++) a[tm] = *(const bf16x8_t*)(At + (mbase+tm*16+nl)*LDW + kel);
      #pragma unroll
      for (int tn=0;tn<8;tn++) b[tn] = *(const bf16x8_t*)(Wt + (tn*16+nl)*LDW + kel);
      #pragma unroll
      for (int tm=0;tm<2;tm++)
        #pragma unroll
        for (int tn=0;tn<8;tn++)
          acc[tm][tn] = __builtin_amdgcn_mfma_f32_16x16x32_bf16(a[tm], b[tn], acc[tm][tn], 0,0,0);
    }
    __syncthreads();
  }
  // epilogue: residual + bias, transpose-free rowwise LN via 16-lane shfl reduction
  float rsum[2][4], rsq[2][4];
  for (int tm=0;tm<2;tm++) for (int p=0;p<4;p++) { rsum[tm][p]=0.f; rsq[tm][p]=0.f; }
  #pragma unroll
  for (int tm=0;tm<2;tm++)
    #pragma unroll
    for (int tn=0;tn<8;tn++) {
      int n = tn*16 + nl;
      float bb = bo[n];
      #pragma unroll
      for (int p=0;p<4;p++) {
        int m = w*32 + tm*16 + q*4 + p;
        float v = acc[tm][tn][p] + bb + pair[(size_t)(r0+m)*128 + n];
        acc[tm][tn][p] = v;
        rsum[tm][p] += v;
        rsq[tm][p]  += v*v;
      }
    }
  for (int msk=1; msk<16; msk<<=1) {
    #pragma unroll
    for (int tm=0;tm<2;tm++)
      #pragma unroll
      for (int p=0;p<4;p++) {
        rsum[tm][p] += __shfl_xor(rsum[tm][p], msk, 64);
        rsq[tm][p]  += __shfl_xor(rsq[tm][p],  msk, 64);
      }
  }
  #pragma unroll
  for (int tm=0;tm<2;tm++)
    #pragma unroll
    for (int p=0;p<4;p++) {
      float mu = rsum[tm][p] * (1.f/128.f);
      float var = rsq[tm][p]*(1.f/128.f) - mu*mu;
      rsum[tm][p] = mu;
      rsq[tm][p] = rsqrtf(var + 1e-5f);
    }
  #pragma unroll
  for (int tm=0;tm<2;tm++)
    #pragma unroll
    for (int tn=0;tn<8;tn++) {
      int n = tn*16 + nl;
      float g = ng[n], b2 = nb_[n];
      #pragma unroll
      for (int p=0;p<4;p++) {
        int m = w*32 + tm*16 + q*4 + p;
        out[(size_t)(r0+m)*128 + n] = (acc[tm][tn][p] - rsum[tm][p]) * rsq[tm][p] * g + b2;
      }
    }
}

extern "C" void kernel_launch(void* const* d_in, const int* in_sizes, int n_in,
                              void* d_out, int out_size, void* d_ws, size_t ws_size,
                              hipStream_t stream) {
  (void)in_sizes; (void)n_in; (void)out_size; (void)ws_size;
  const float* pair   = (const float*)d_in[0];
  const float* ln_l_g = (const float*)d_in[1];
  const float* ln_l_b = (const float*)d_in[2];
  const float* ln_r_g = (const float*)d_in[3];
  const float* ln_r_b = (const float*)d_in[4];
  const float* Wl = (const float*)d_in[5];
  const float* bl = (const float*)d_in[6];
  const float* Wr = (const float*)d_in[7];
  const float* br = (const float*)d_in[8];
  const float* Wg = (const float*)d_in[9];
  const float* bg = (const float*)d_in[10];
  const float* Wo = (const float*)d_in[11];
  const float* bo = (const float*)d_in[12];
  const float* n_g = (const float*)d_in[13];
  const float* n_b = (const float*)d_in[14];

  char* ws = (char*)d_ws;
  const size_t SZ = (size_t)M_*128*sizeof(u16);         // 37,748,736 B
  u16*  og_t    = (u16*)(ws);                           // written by k_einsum
  u16*  gate_t  = (u16*)(ws + SZ);
  u16*  wcat    = (u16*)(ws + 2*SZ);
  float* bcat   = (float*)(ws + 2*SZ + 98304);
  float* sgp    = (float*)(ws + 2*SZ + 98304 + 1536);
  u16*  wot     = (u16*)(ws + 2*SZ + 98304 + 1536 + 512);

  // left_t / right_t live in d_out until k_final overwrites it with the result
  u16* left_t   = (u16*)d_out;
  u16* right_t  = (u16*)d_out + (size_t)M_*128;

  k_prep1<<<256, 256, 0, stream>>>(ln_l_g, ln_r_g, Wl, Wr, Wg, Wo, wcat, wot);
  k_prep2<<<2, 512, 0, stream>>>(ln_l_b, ln_r_b, Wl, Wr, Wg, bl, br, bg, bcat, sgp);
  k_projln<<<1152, 256, 0, stream>>>(pair, wcat, bcat, sgp, left_t, right_t, gate_t);
  k_einsum<<<1152, 256, 0, stream>>>(left_t, right_t, gate_t, og_t);
  k_final<<<1152, 256, 0, stream>>>(og_t, wot, pair, bo, n_g, n_b, (float*)d_out);
}